// Round 1
// baseline (1128.250 us; speedup 1.0000x reference)
//
#include <hip/hip_runtime.h>

#define NN 300000
#define FF 64
#define EE 2400000
#define FEA 8
#define RAWCAP 131072   // >= 8*129*97 = 100104 guaranteed by IMG_W/H bounds
#define LCAP 4096

__device__ __forceinline__ unsigned fenc(float f) {
  unsigned b = __float_as_uint(f);
  return (b & 0x80000000u) ? ~b : (b | 0x80000000u);
}
__device__ __forceinline__ float fdec(unsigned e) {
  unsigned b = (e & 0x80000000u) ? (e ^ 0x80000000u) : ~e;
  return __uint_as_float(b);
}

__global__ void init_hdr_k(unsigned* hdr) {
  if (threadIdx.x == 0) {
    hdr[0] = 0xFFFFFFFFu; hdr[1] = 0xFFFFFFFFu;  // min enc
    hdr[2] = 0u;          hdr[3] = 0u;           // max enc
  }
}

__global__ void minmax_k(const float* __restrict__ pos, unsigned* hdr) {
  int t = blockIdx.x * blockDim.x + threadIdx.x;
  float mnx = 1e30f, mny = 1e30f, mxx = -1e30f, mxy = -1e30f;
  for (int i = t; i < NN; i += gridDim.x * blockDim.x) {
    float px = pos[i * 3 + 1], py = pos[i * 3 + 2];
    mnx = fminf(mnx, px); mny = fminf(mny, py);
    mxx = fmaxf(mxx, px); mxy = fmaxf(mxy, py);
  }
  for (int o = 1; o < 64; o <<= 1) {
    mnx = fminf(mnx, __shfl_xor(mnx, o));
    mny = fminf(mny, __shfl_xor(mny, o));
    mxx = fmaxf(mxx, __shfl_xor(mxx, o));
    mxy = fmaxf(mxy, __shfl_xor(mxy, o));
  }
  if ((threadIdx.x & 63) == 0) {
    atomicMin(&hdr[0], fenc(mnx));
    atomicMin(&hdr[1], fenc(mny));
    atomicMax(&hdr[2], fenc(mxx));
    atomicMax(&hdr[3], fenc(mxy));
  }
}

__global__ void dims_k(unsigned* hdr) {
  if (threadIdx.x == 0 && blockIdx.x == 0) {
    float mnx = fdec(hdr[0]), mny = fdec(hdr[1]);
    float mxx = fdec(hdr[2]), mxy = fdec(hdr[3]);
    int d0 = (int)(floorf((mxx - mnx) / 5.0f) + 1.0f);
    int d1 = (int)(floorf((mxy - mny) / 5.0f) + 1.0f);
    hdr[4] = (unsigned)d0;
    hdr[5] = (unsigned)d1;
    ((float*)hdr)[6] = mnx;
    ((float*)hdr)[7] = mny;
  }
}

__global__ void raw_k(const float* __restrict__ pos, const int* __restrict__ batch,
                      const unsigned* __restrict__ hdr, int* __restrict__ cluster,
                      unsigned* __restrict__ flags) {
  int i = blockIdx.x * blockDim.x + threadIdx.x;
  if (i >= NN) return;
  float mnx = ((const float*)hdr)[6], mny = ((const float*)hdr)[7];
  int d0 = (int)hdr[4], d1 = (int)hdr[5];
  int c0 = (int)floorf((pos[i * 3 + 1] - mnx) / 5.0f);
  int c1 = (int)floorf((pos[i * 3 + 2] - mny) / 5.0f);
  int raw = batch[i] * (d0 * d1) + c0 * d1 + c1;
  cluster[i] = raw;
  flags[raw] = 1u;
}

// generic exclusive-scan pieces (1024 elems per block)
__global__ void scan_part(const unsigned* __restrict__ in, unsigned* __restrict__ out,
                          unsigned* __restrict__ bsum, int ntot, unsigned* __restrict__ total_out) {
  __shared__ unsigned sc[256];
  int base = blockIdx.x * 1024 + threadIdx.x * 4;
  unsigned v[4]; unsigned s = 0;
#pragma unroll
  for (int k = 0; k < 4; k++) {
    int i = base + k;
    v[k] = (i < ntot) ? in[i] : 0u;
    s += v[k];
  }
  sc[threadIdx.x] = s;
  __syncthreads();
  unsigned xv = s;
  for (int o = 1; o < 256; o <<= 1) {
    unsigned y = (threadIdx.x >= o) ? sc[threadIdx.x - o] : 0u;
    __syncthreads();
    xv += y;
    sc[threadIdx.x] = xv;
    __syncthreads();
  }
  unsigned run = xv - s;
#pragma unroll
  for (int k = 0; k < 4; k++) {
    int i = base + k;
    if (i < ntot) out[i] = run;
    run += v[k];
  }
  if (threadIdx.x == 255) {
    if (bsum) bsum[blockIdx.x] = xv;
    if (total_out && blockIdx.x == 0) *total_out = xv;
  }
}

__global__ void scan_add(unsigned* __restrict__ out, const unsigned* __restrict__ bsum, int ntot) {
  unsigned add = bsum[blockIdx.x];
  int base = blockIdx.x * 1024;
  for (int k = threadIdx.x; k < 1024; k += 256) {
    int i = base + k;
    if (i < ntot) out[i] += add;
  }
}

__global__ void node_accum_k(const float* __restrict__ x, const float* __restrict__ pos,
                             const int* __restrict__ batch, const unsigned* __restrict__ rank,
                             int* __restrict__ cluster, unsigned* __restrict__ cnt,
                             unsigned long long* __restrict__ possum,
                             float* __restrict__ out_x, float* __restrict__ out_batch) {
  int tid = blockIdx.x * blockDim.x + threadIdx.x;
  if (tid >= NN * FF) return;
  int i = tid >> 6, f = tid & 63;
  int raw = cluster[i];
  int cl = (int)rank[raw];
  unsigned ev = fenc(x[tid]);
  atomicMax((unsigned*)&out_x[(size_t)cl * FF + f], ev);
  if (f == 0) cluster[i] = cl;          // same-wave lanes already read raw
  if (f < 3) {
    float p = pos[i * 3 + f];
    long long fp = llrintf(p * 65536.0f);
    atomicAdd(&possum[cl * 3 + f], (unsigned long long)fp);
  } else if (f == 3) {
    atomicAdd(&cnt[cl], 1u);
  } else if (f == 4) {
    out_batch[cl] = (float)batch[i];    // same value from all writers
  }
}

__global__ void node_final_k(const unsigned* __restrict__ cnt,
                             const unsigned long long* __restrict__ possum,
                             const unsigned* __restrict__ hdr,
                             float* __restrict__ out_x, float* __restrict__ out_pos,
                             float* __restrict__ out_batch) {
  int tid = blockIdx.x * blockDim.x + threadIdx.x;
  if (tid >= NN * FF) return;
  int r = tid >> 6, f = tid & 63;
  unsigned ncl = hdr[8];
  if ((unsigned)r < ncl) {
    unsigned e = ((unsigned*)out_x)[tid];
    out_x[tid] = fdec(e);
    if (f < 3) {
      unsigned c = cnt[r];
      float cf = (float)(c > 0u ? c : 1u);
      float m = (float)((double)(long long)possum[r * 3 + f] / 65536.0 / (double)cf);
      if (f > 0) m = floorf(m / 4.0f);
      out_pos[r * 3 + f] = m;
    }
  } else {
    if (f < 3) out_pos[r * 3 + f] = 0.0f;
    if (f == 0) out_batch[r] = -1.0f;
  }
}

__global__ void edge_init_k(float* __restrict__ out_ei, float* __restrict__ out_ea) {
  int t = blockIdx.x * blockDim.x + threadIdx.x;
  if (t < 2 * EE) out_ei[t] = -1.0f;
  int u = t - 2 * EE;
  if (u >= 0 && u < EE * FEA) out_ea[u] = 0.0f;
}

__global__ void edge_cnt_k(const int* __restrict__ ei, const int* __restrict__ cluster,
                           unsigned* __restrict__ cs_cnt) {
  int t = blockIdx.x * blockDim.x + threadIdx.x;
  if (t >= EE) return;
  int s = cluster[ei[t]];
  int d = cluster[ei[EE + t]];
  if (s == d) s = NN;
  atomicAdd(&cs_cnt[s], 1u);
}

__global__ void edge_scatter_k(const int* __restrict__ ei, const int* __restrict__ cluster,
                               const unsigned* __restrict__ cs_off, unsigned* __restrict__ cs_fill,
                               unsigned long long* __restrict__ keys) {
  int t = blockIdx.x * blockDim.x + threadIdx.x;
  if (t >= EE) return;
  int s = cluster[ei[t]];
  int d = cluster[ei[EE + t]];
  if (s == d) { s = NN; d = NN; }
  unsigned p = cs_off[s] + atomicAdd(&cs_fill[s], 1u);
  keys[p] = ((unsigned long long)(unsigned)d << 22) | (unsigned)t;
}

__global__ void __launch_bounds__(256)
bucket_sort_k(unsigned long long* __restrict__ keys,
              const unsigned* __restrict__ cs_off,
              unsigned* __restrict__ grp_cnt) {
  __shared__ unsigned long long sm[LCAP];
  __shared__ unsigned long long rb[256];
  __shared__ int ri[256];
  __shared__ unsigned s4[4];
  for (int b = blockIdx.x; b < NN; b += gridDim.x) {   // skip self-loop bucket b==NN
    unsigned o0 = cs_off[b];
    int len = (int)(cs_off[b + 1] - o0);
    if (len <= 1) {
      if (len == 1 && threadIdx.x == 0) grp_cnt[b] = 1u;
      continue;
    }
    if (len <= LCAP) {
      int np = 1; while (np < len) np <<= 1;
      for (int i = threadIdx.x; i < np; i += 256)
        sm[i] = (i < len) ? keys[o0 + i] : ~0ULL;
      __syncthreads();
      for (int k = 2; k <= np; k <<= 1) {
        for (int j = k >> 1; j > 0; j >>= 1) {
          for (int i = threadIdx.x; i < np; i += 256) {
            int ixj = i ^ j;
            if (ixj > i) {
              unsigned long long a = sm[i], c = sm[ixj];
              bool up = ((i & k) == 0);
              if (up ? (a > c) : (a < c)) { sm[i] = c; sm[ixj] = a; }
            }
          }
          __syncthreads();
        }
      }
      unsigned g = 0;
      for (int i = threadIdx.x; i < len; i += 256) {
        unsigned long long kk = sm[i];
        keys[o0 + i] = kk;
        unsigned cd = (unsigned)(kk >> 22);
        if (i == 0 || (unsigned)(sm[i - 1] >> 22) != cd) g++;
      }
      for (int o = 32; o > 0; o >>= 1) g += __shfl_down(g, o);
      if ((threadIdx.x & 63) == 0) s4[threadIdx.x >> 6] = g;
      __syncthreads();
      if (threadIdx.x == 0) grp_cnt[b] = s4[0] + s4[1] + s4[2] + s4[3];
      __syncthreads();
    } else {
      // insurance path (unreachable for this data): block selection sort
      for (int p = 0; p < len - 1; p++) {
        unsigned long long best = ~0ULL; int bi = -1;
        for (int i = p + threadIdx.x; i < len; i += 256) {
          unsigned long long v = keys[o0 + i];
          if (v < best) { best = v; bi = i; }
        }
        rb[threadIdx.x] = best; ri[threadIdx.x] = bi;
        __syncthreads();
        for (int sd = 128; sd > 0; sd >>= 1) {
          if (threadIdx.x < sd && rb[threadIdx.x + sd] < rb[threadIdx.x]) {
            rb[threadIdx.x] = rb[threadIdx.x + sd]; ri[threadIdx.x] = ri[threadIdx.x + sd];
          }
          __syncthreads();
        }
        if (threadIdx.x == 0) {
          int m = ri[0];
          unsigned long long tmp = keys[o0 + p];
          keys[o0 + p] = rb[0];
          keys[o0 + m] = tmp;
        }
        __syncthreads();
      }
      unsigned g = 0;
      for (int i = threadIdx.x; i < len; i += 256) {
        unsigned cd = (unsigned)(keys[o0 + i] >> 22);
        if (i == 0 || (unsigned)(keys[o0 + i - 1] >> 22) != cd) g++;
      }
      for (int o = 32; o > 0; o >>= 1) g += __shfl_down(g, o);
      if ((threadIdx.x & 63) == 0) s4[threadIdx.x >> 6] = g;
      __syncthreads();
      if (threadIdx.x == 0) grp_cnt[b] = s4[0] + s4[1] + s4[2] + s4[3];
      __syncthreads();
    }
  }
}

__global__ void __launch_bounds__(256)
bucket_emit_k(const unsigned long long* __restrict__ keys,
              const unsigned* __restrict__ cs_off,
              const unsigned* __restrict__ grp_base,
              const float* __restrict__ ea,
              float* __restrict__ out_src, float* __restrict__ out_dst,
              float* __restrict__ out_ea) {
  __shared__ unsigned sc[256];
  __shared__ unsigned s_carry;
  for (int b = blockIdx.x; b < NN; b += gridDim.x) {
    unsigned o0 = cs_off[b];
    int len = (int)(cs_off[b + 1] - o0);
    if (len == 0) continue;
    unsigned base = grp_base[b];
    if (threadIdx.x == 0) s_carry = 0;
    __syncthreads();
    for (int c0 = 0; c0 < len; c0 += 256) {
      int i = c0 + threadIdx.x;
      unsigned cd = 0; bool newg = false;
      if (i < len) {
        unsigned long long kk = keys[o0 + i];
        cd = (unsigned)(kk >> 22);
        newg = (i == 0) || ((unsigned)(keys[o0 + i - 1] >> 22) != cd);
      }
      unsigned flag = newg ? 1u : 0u;
      sc[threadIdx.x] = flag;
      __syncthreads();
      unsigned xv = flag;
      for (int o = 1; o < 256; o <<= 1) {
        unsigned y = (threadIdx.x >= o) ? sc[threadIdx.x - o] : 0u;
        __syncthreads();
        xv += y;
        sc[threadIdx.x] = xv;
        __syncthreads();
      }
      unsigned carry_old = s_carry;
      if (newg) {
        float a0=0,a1=0,a2=0,a3=0,a4=0,a5=0,a6=0,a7=0;
        int j = i;
        while (j < len) {
          unsigned long long k2 = keys[o0 + j];
          if ((unsigned)(k2 >> 22) != cd) break;
          unsigned eid = (unsigned)(k2 & 0x3FFFFFu);
          const float* p = &ea[(size_t)eid * FEA];
          a0+=p[0];a1+=p[1];a2+=p[2];a3+=p[3];a4+=p[4];a5+=p[5];a6+=p[6];a7+=p[7];
          j++;
        }
        unsigned row = base + carry_old + xv - 1u;
        out_src[row] = (float)b;
        out_dst[row] = (float)cd;
        float* q = &out_ea[(size_t)row * FEA];
        q[0]=a0;q[1]=a1;q[2]=a2;q[3]=a3;q[4]=a4;q[5]=a5;q[6]=a6;q[7]=a7;
      }
      __syncthreads();
      if (threadIdx.x == 255) s_carry = carry_old + xv;
      __syncthreads();
    }
  }
}

extern "C" void kernel_launch(void* const* d_in, const int* in_sizes, int n_in,
                              void* d_out, int out_size, void* d_ws, size_t ws_size,
                              hipStream_t stream) {
  const float* x   = (const float*)d_in[0];
  const float* pos = (const float*)d_in[1];
  const int* batch = (const int*)d_in[2];
  const int* ei    = (const int*)d_in[3];
  const float* ea  = (const float*)d_in[4];
  float* out = (float*)d_out;

  const size_t OX = 0;
  const size_t OP = (size_t)NN * FF;
  const size_t OB = OP + (size_t)NN * 3;
  const size_t OE = OB + (size_t)NN;
  const size_t OA = OE + (size_t)2 * EE;

  char* w = (char*)d_ws;
  size_t woff = 0;
  auto alloc = [&](size_t bytes) -> void* {
    void* p = w + woff;
    woff += (bytes + 255) & ~(size_t)255;
    return p;
  };
  // zeroed region (one memset)
  unsigned* rank    = (unsigned*)alloc((size_t)RAWCAP * 4);
  unsigned* cnt     = (unsigned*)alloc((size_t)NN * 4);
  unsigned* cs_cnt  = (unsigned*)alloc((size_t)(NN + 1) * 4);
  unsigned* cs_fill = (unsigned*)alloc((size_t)(NN + 1) * 4);
  unsigned* grp_cnt = (unsigned*)alloc((size_t)(NN + 1) * 4);
  unsigned long long* possum = (unsigned long long*)alloc((size_t)NN * 3 * 8);
  size_t zero_bytes = woff;
  // written-before-read region
  int* cluster      = (int*)alloc((size_t)NN * 4);
  unsigned* cs_off  = (unsigned*)alloc((size_t)(NN + 2) * 4);
  unsigned* grp_base= (unsigned*)alloc((size_t)(NN + 2) * 4);
  unsigned* bsum    = (unsigned*)alloc(4096 * 4);
  unsigned* hdr     = (unsigned*)alloc(256);
  unsigned long long* keys = (unsigned long long*)alloc((size_t)EE * 8);

  hipMemsetAsync(d_ws, 0, zero_bytes, stream);
  hipMemsetAsync(d_out, 0, (size_t)NN * FF * 4, stream);  // new_x region = encoded identity

  init_hdr_k<<<1, 64, 0, stream>>>(hdr);
  minmax_k<<<512, 256, 0, stream>>>(pos, hdr);
  dims_k<<<1, 64, 0, stream>>>(hdr);
  raw_k<<<(NN + 255) / 256, 256, 0, stream>>>(pos, batch, hdr, cluster, rank);

  auto scan = [&](unsigned* in_, unsigned* out_, int ntot, unsigned* total_out) {
    int nb = (ntot + 1023) / 1024;
    scan_part<<<nb, 256, 0, stream>>>(in_, out_, bsum, ntot, nullptr);
    scan_part<<<1, 256, 0, stream>>>(bsum, bsum, nullptr, nb, total_out);
    scan_add<<<nb, 256, 0, stream>>>(out_, bsum, ntot);
  };
  scan(rank, rank, RAWCAP, hdr + 8);  // rank[raw] = cluster id; total -> n_clusters

  node_accum_k<<<(NN * FF + 255) / 256, 256, 0, stream>>>(x, pos, batch, rank, cluster,
                                                          cnt, possum, out + OX, out + OB);
  node_final_k<<<(NN * FF + 255) / 256, 256, 0, stream>>>(cnt, possum, hdr,
                                                          out + OX, out + OP, out + OB);

  edge_init_k<<<((2 * EE + EE * FEA) + 255) / 256, 256, 0, stream>>>(out + OE, out + OA);
  edge_cnt_k<<<(EE + 255) / 256, 256, 0, stream>>>(ei, cluster, cs_cnt);
  scan(cs_cnt, cs_off, NN + 1, nullptr);
  edge_scatter_k<<<(EE + 255) / 256, 256, 0, stream>>>(ei, cluster, cs_off, cs_fill, keys);
  bucket_sort_k<<<2048, 256, 0, stream>>>(keys, cs_off, grp_cnt);
  scan(grp_cnt, grp_base, NN + 1, nullptr);
  bucket_emit_k<<<2048, 256, 0, stream>>>(keys, cs_off, grp_base, ea,
                                          out + OE, out + OE + EE, out + OA);
}